// Round 6
// baseline (495.598 us; speedup 1.0000x reference)
//
#include <hip/hip_runtime.h>

#define NUM_GRAPHS 1024
#define BIN_BITS 10
#define BIN_SIZE (1 << BIN_BITS)      // 1024 nodes per bin
#define EB 4096                       // edges per binning block
#define STH 512                       // scatter threads (8 waves)
#define EPT 8                         // edges per thread in scatter (EB/STH)
#define SWAVES 8                      // scatter waves per block
#define CURS 16                       // cursor stride in ints (64 B = 1 line)
#define ACCTH 256                     // accum threads (4 waves)
#define ACCW 4                        // waves per accum block

typedef int v4i __attribute__((ext_vector_type(4)));  // native vec for nt-load

// ---------------------------------------------------------------------------
// bin_scatter v8 (control: unchanged logic; cursors are now RELATIVE counts
// initialized to 0 by hipMemsetAsync, so the reserve adds t*cap here).
// Zero per-edge atomics: ballot-match ranking + per-wave hist, plain stores
// through L2 (r4 lesson: NEVER nt-store scattered sub-line data).
// packed = (dst_local << 19) | src.
// ---------------------------------------------------------------------------
__global__ void __launch_bounds__(STH, 6) bin_scatter(const int* __restrict__ src,
                                                      const int* __restrict__ dst,
                                                      int* __restrict__ packed,
                                                      int* __restrict__ cursor,
                                                      int E, int cap, int nb) {
    __shared__ int hist[SWAVES][512];     // per-wave counts (plain RMW)
    __shared__ int wbase[SWAVES][512];    // per-wave global write base per bin

    const int t = threadIdx.x;
    const int lane = t & 63;
    const int wave = t >> 6;
    const int b0 = blockIdx.x * EB;
    const int myBase = b0 + t * EPT;

    for (int j = t; j < SWAVES * 512; j += STH) (&hist[0][0])[j] = 0;
    __syncthreads();

    // ---- load 8 edges per thread (two int4 each of src/dst) ----
    int dbuf[EPT], sbuf[EPT];
    const bool full = (myBase + EPT <= E);
    if (full) {
        *(int4*)(dbuf)     = *(const int4*)(dst + myBase);
        *(int4*)(dbuf + 4) = *(const int4*)(dst + myBase + 4);
        *(int4*)(sbuf)     = *(const int4*)(src + myBase);
        *(int4*)(sbuf + 4) = *(const int4*)(src + myBase + 4);
    } else {
#pragma unroll
        for (int i = 0; i < EPT; ++i) {
            int e = myBase + i;
            bool ok = e < E;
            dbuf[i] = ok ? dst[e] : 0;
            sbuf[i] = ok ? src[e] : 0;
        }
    }

    // ---- pass A: ballot-match ranking, plain LDS RMW (no atomics) ----
    int pv[EPT];                   // packed edge values
    int bnlp[EPT];                 // (bn << 16) | lp, or -1 if invalid
#pragma unroll
    for (int k = 0; k < EPT; ++k) {
        int e = myBase + k;
        bool ok = full || (e < E);
        int d = dbuf[k];
        int bn = ((unsigned)d) >> BIN_BITS;            // < 512
        pv[k] = ((d & (BIN_SIZE - 1)) << 19) | sbuf[k];
        unsigned long long m = __ballot(ok);
#pragma unroll
        for (int bb = 0; bb < 9; ++bb) {
            unsigned long long bm = __ballot((bn >> bb) & 1);
            m &= ((bn >> bb) & 1) ? bm : ~bm;
        }
        int rank = (int)__popcll(m & ((1ull << lane) - 1ull));
        int cnt  = (int)__popcll(m);
        int leader = __ffsll((unsigned long long)m) - 1;
        int old = hist[wave][bn];                      // group lanes: same addr
        if (ok && lane == leader) hist[wave][bn] = old + cnt;
        bnlp[k] = ok ? ((bn << 16) | (old + rank)) : -1;
    }
    __syncthreads();

    // ---- combine: per-bin cross-wave prefix + single cursor reserve ----
    {
        int c[SWAVES];
        int total = 0;
#pragma unroll
        for (int w = 0; w < SWAVES; ++w) { c[w] = hist[w][t]; total += c[w]; }
        int base = t * cap;                 // cursors are relative counts now
        if (t < nb && total > 0) base += atomicAdd(&cursor[t * CURS], total);
        int acc = base;
#pragma unroll
        for (int w = 0; w < SWAVES; ++w) { wbase[w][t] = acc; acc += c[w]; }
    }
    __syncthreads();

    // ---- pass B: direct scattered stores THROUGH L2 (plain, not nt) ----
    if (full) {
#pragma unroll
        for (int k = 0; k < EPT; ++k) {
            int bn = ((unsigned)bnlp[k]) >> 16;
            int lp = bnlp[k] & 0xFFFF;
            int pos = wbase[wave][bn] + lp;
            if (pos < (bn + 1) * cap)          // overflow guard (~28 sigma)
                packed[pos] = pv[k];
        }
    } else {
#pragma unroll
        for (int k = 0; k < EPT; ++k) {
            if (bnlp[k] >= 0) {
                int bn = ((unsigned)bnlp[k]) >> 16;
                int lp = bnlp[k] & 0xFFFF;
                int pos = wbase[wave][bn] + lp;
                if (pos < (bn + 1) * cap)
                    packed[pos] = pv[k];
            }
        }
    }
}

// ---------------------------------------------------------------------------
// Accum v8: v7's zero-atomic LDS-plane scatter-add, now
//  (a) SOFTWARE-PIPELINED one round ahead: packed[r+1] load + x gathers[r+1]
//      issue before round r's ballot/RMW work (hides the serial
//      load->gather->RMW chain that made v7 latency-bound at 8 waves/CU);
//  (b) gathers float4 x[src] DIRECTLY (x = 8 MB, L2-resident; the bf16 x16
//      copy + prep kernel are deleted);
//  (c) validity ballot removed: invalid lanes add 0.0f to node 0.
// Explicit A/B register sets (rule #20: no runtime-indexed arrays).
// ---------------------------------------------------------------------------
#define LOADR(B, PE, VM) do {                                              \
    int _i = (B) + lane * 4;                                               \
    if (_i + 3 < s1) {                                                     \
        v4i _p4 = __builtin_nontemporal_load((const v4i*)(packed + _i));   \
        PE[0] = _p4.x; PE[1] = _p4.y; PE[2] = _p4.z; PE[3] = _p4.w;        \
        VM = 0xF;                                                          \
    } else {                                                               \
        VM = 0;                                                            \
        PE[0] = (_i + 0 < s1) ? (VM |= 1, packed[_i + 0]) : 0;             \
        PE[1] = (_i + 1 < s1) ? (VM |= 2, packed[_i + 1]) : 0;             \
        PE[2] = (_i + 2 < s1) ? (VM |= 4, packed[_i + 2]) : 0;             \
        PE[3] = (_i + 3 < s1) ? (VM |= 8, packed[_i + 3]) : 0;             \
    }                                                                      \
} while (0)

#define GATHR(PE, G) do {                                                  \
    G[0] = x[min(PE[0] & 0x7FFFF, N - 1)];                                 \
    G[1] = x[min(PE[1] & 0x7FFFF, N - 1)];                                 \
    G[2] = x[min(PE[2] & 0x7FFFF, N - 1)];                                 \
    G[3] = x[min(PE[3] & 0x7FFFF, N - 1)];                                 \
} while (0)

#define PROCR(PE, G, VM) do {                                              \
    _Pragma("unroll")                                                      \
    for (int k = 0; k < 4; ++k) {                                          \
        int p = PE[k];                                                     \
        int dl = (((unsigned)p) >> 19) & (BIN_SIZE - 1);                   \
        unsigned long long m = ~0ull;                                      \
        _Pragma("unroll")                                                  \
        for (int bb = 0; bb < BIN_BITS; ++bb) {                            \
            unsigned long long bm = __ballot((dl >> bb) & 1);              \
            m &= ((dl >> bb) & 1) ? bm : ~bm;                              \
        }                                                                  \
        int rank = (int)__popcll(m & ((1ull << lane) - 1ull));             \
        float sc = ((VM >> k) & 1) ? 1.0f : 0.0f;                          \
        float v0 = G[k].x * sc, v1 = G[k].y * sc;                          \
        float v2 = G[k].z * sc, v3 = G[k].w * sc;                          \
        float4* pp = (float4*)&planes[wave][dl][0];                        \
        for (int pass = 0; __any(rank >= pass); ++pass) {                  \
            if (rank == pass) {                                            \
                float4 a = *pp;                                            \
                a.x += v0; a.y += v1; a.z += v2; a.w += v3;                \
                *pp = a;                                                   \
            }                                                              \
        }                                                                  \
    }                                                                      \
} while (0)

__global__ void __launch_bounds__(ACCTH) bin_accum_mlp_pool(
        const float4* __restrict__ x,
        const int* __restrict__ packed,
        const int* __restrict__ cursor,
        const int* __restrict__ batch,
        const float* __restrict__ eps_p,
        const float* __restrict__ W1, const float* __restrict__ b1,
        const float* __restrict__ W2, const float* __restrict__ b2,
        float* __restrict__ gsum, float* __restrict__ gcnt,
        int N, int cap) {
    __shared__ float planes[ACCW][BIN_SIZE][4];   // 64 KB, per-wave private

    const int bin = blockIdx.x;
    const int t = threadIdx.x;
    const int lane = t & 63;
    const int wave = t >> 6;

    // zero planes: 4096 float4s / 256 threads = 16 each
    {
        float4* pz = (float4*)&planes[0][0][0];
        float4 z; z.x = 0.f; z.y = 0.f; z.z = 0.f; z.w = 0.f;
#pragma unroll
        for (int i = 0; i < 16; ++i) pz[t + i * ACCTH] = z;
    }
    __syncthreads();

    const int start = bin * cap;
    int cnt = cursor[bin * CURS];                 // relative count
    if (cnt > cap) cnt = cap;
    if (cnt < 0) cnt = 0;
    const int end = start + cnt;

    // contiguous per-wave segments, 16B-aligned bases
    int seg = ((cnt + ACCW - 1) / ACCW + 3) & ~3;
    int s0 = start + wave * seg;
    int s1 = s0 + seg; if (s1 > end) s1 = end;

    // ---- pipelined edge loop: load/gather round r+1 before processing r ---
    if (s0 < s1) {
        int peA[4], peB[4], vmA, vmB;
        float4 gA[4], gB[4];
        int b = s0;
        LOADR(b, peA, vmA);
        GATHR(peA, gA);
        for (;;) {
            int b1n = b + 256;
            if (b1n < s1) { LOADR(b1n, peB, vmB); GATHR(peB, gB); }
            PROCR(peA, gA, vmA);
            if (b1n >= s1) break;
            int b2n = b1n + 256;
            if (b2n < s1) { LOADR(b2n, peA, vmA); GATHR(peA, gA); }
            PROCR(peB, gB, vmB);
            if (b2n >= s1) break;
            b = b2n;
        }
    }
    __syncthreads();

    // ---- reduce 4 planes + MLP + pool; 4 node-batches of 256 ----
    const float eps = eps_p[0];
    for (int half = 0; half < 4; ++half) {
        int node = t + half * ACCTH;           // 0..1023
        float4 a = *(const float4*)&planes[0][node][0];
#pragma unroll
        for (int w = 1; w < ACCW; ++w) {
            float4 bq = *(const float4*)&planes[w][node][0];
            a.x += bq.x; a.y += bq.y; a.z += bq.z; a.w += bq.w;
        }

        int n = bin * BIN_SIZE + node;         // one node per thread
        bool valid = n < N;
        float o0 = 0.f, o1 = 0.f, o2 = 0.f, o3 = 0.f;
        int g = -1;
        if (valid) {
            float4 xv = x[n];
            float h0 = (1.0f + eps) * xv.x + a.x;
            float h1 = (1.0f + eps) * xv.y + a.y;
            float h2 = (1.0f + eps) * xv.z + a.z;
            float h3 = (1.0f + eps) * xv.w + a.w;

            float tmp[16];
#pragma unroll
            for (int j = 0; j < 16; ++j) {
                float v = b1[j] + h0 * W1[j] + h1 * W1[16 + j] + h2 * W1[32 + j] + h3 * W1[48 + j];
                tmp[j] = v > 0.0f ? v : 0.0f;
            }
            float o[4];
#pragma unroll
            for (int j = 0; j < 4; ++j) {
                float v = b2[j];
#pragma unroll
                for (int k = 0; k < 16; ++k) v += tmp[k] * W2[k * 4 + j];
                o[j] = v > 0.0f ? v : 0.0f;
            }
            o0 = o[0]; o1 = o[1]; o2 = o[2]; o3 = o[3];
            g = batch[n];
        }

        // batch is sorted -> waves almost always graph-uniform
        int g0 = __shfl(g, 0);
        bool uni = __all(g == g0);
        if (uni && g0 >= 0) {
#pragma unroll
            for (int off = 32; off > 0; off >>= 1) {
                o0 += __shfl_down(o0, off);
                o1 += __shfl_down(o1, off);
                o2 += __shfl_down(o2, off);
                o3 += __shfl_down(o3, off);
            }
            if (lane == 0) {
                unsafeAtomicAdd(&gsum[(size_t)g0 * 4 + 0], o0);
                unsafeAtomicAdd(&gsum[(size_t)g0 * 4 + 1], o1);
                unsafeAtomicAdd(&gsum[(size_t)g0 * 4 + 2], o2);
                unsafeAtomicAdd(&gsum[(size_t)g0 * 4 + 3], o3);
                unsafeAtomicAdd(&gcnt[g0], 64.0f);
            }
        } else if (valid) {
            unsafeAtomicAdd(&gsum[(size_t)g * 4 + 0], o0);
            unsafeAtomicAdd(&gsum[(size_t)g * 4 + 1], o1);
            unsafeAtomicAdd(&gsum[(size_t)g * 4 + 2], o2);
            unsafeAtomicAdd(&gsum[(size_t)g * 4 + 3], o3);
            unsafeAtomicAdd(&gcnt[g], 1.0f);
        }
    }
}

// ---------------------------------------------------------------------------
// pooled = sums / max(cnt,1); out = log_softmax per graph.
// ---------------------------------------------------------------------------
__global__ void pool_softmax_kernel(const float* __restrict__ gsum,
                                    const float* __restrict__ gcnt,
                                    float* __restrict__ out) {
    int g = blockIdx.x * blockDim.x + threadIdx.x;
    if (g >= NUM_GRAPHS) return;
    float c = fmaxf(gcnt[g], 1.0f);
    float p0 = gsum[g * 4 + 0] / c;
    float p1 = gsum[g * 4 + 1] / c;
    float p2 = gsum[g * 4 + 2] / c;
    float p3 = gsum[g * 4 + 3] / c;
    float m = fmaxf(fmaxf(p0, p1), fmaxf(p2, p3));
    float s = expf(p0 - m) + expf(p1 - m) + expf(p2 - m) + expf(p3 - m);
    float lse = m + logf(s);
    out[g * 4 + 0] = p0 - lse;
    out[g * 4 + 1] = p1 - lse;
    out[g * 4 + 2] = p2 - lse;
    out[g * 4 + 3] = p3 - lse;
}

// ---------------------------------------------------------------------------
// Fallback kernels (ws too small): direct atomic scatter + separate MLP/pool.
// ---------------------------------------------------------------------------
__global__ void edge_scatter_kernel(const float4* __restrict__ x,
                                    const int* __restrict__ src,
                                    const int* __restrict__ dst,
                                    float* __restrict__ agg,
                                    int E) {
    int t = blockIdx.x * blockDim.x + threadIdx.x;
    int e = t * 4;
    if (e + 3 < E) {
        int4 s = *(const int4*)(src + e);
        int4 d = *(const int4*)(dst + e);
        float4 xv;
        xv = x[s.x];
        unsafeAtomicAdd(&agg[(size_t)d.x * 4 + 0], xv.x);
        unsafeAtomicAdd(&agg[(size_t)d.x * 4 + 1], xv.y);
        unsafeAtomicAdd(&agg[(size_t)d.x * 4 + 2], xv.z);
        unsafeAtomicAdd(&agg[(size_t)d.x * 4 + 3], xv.w);
        xv = x[s.y];
        unsafeAtomicAdd(&agg[(size_t)d.y * 4 + 0], xv.x);
        unsafeAtomicAdd(&agg[(size_t)d.y * 4 + 1], xv.y);
        unsafeAtomicAdd(&agg[(size_t)d.y * 4 + 2], xv.z);
        unsafeAtomicAdd(&agg[(size_t)d.y * 4 + 3], xv.w);
        xv = x[s.z];
        unsafeAtomicAdd(&agg[(size_t)d.z * 4 + 0], xv.x);
        unsafeAtomicAdd(&agg[(size_t)d.z * 4 + 1], xv.y);
        unsafeAtomicAdd(&agg[(size_t)d.z * 4 + 2], xv.z);
        unsafeAtomicAdd(&agg[(size_t)d.z * 4 + 3], xv.w);
        xv = x[s.w];
        unsafeAtomicAdd(&agg[(size_t)d.w * 4 + 0], xv.x);
        unsafeAtomicAdd(&agg[(size_t)d.w * 4 + 1], xv.y);
        unsafeAtomicAdd(&agg[(size_t)d.w * 4 + 2], xv.z);
        unsafeAtomicAdd(&agg[(size_t)d.w * 4 + 3], xv.w);
    } else {
        for (int i = e; i < E; ++i) {
            int sv = src[i], dv = dst[i];
            float4 xv = x[sv];
            unsafeAtomicAdd(&agg[(size_t)dv * 4 + 0], xv.x);
            unsafeAtomicAdd(&agg[(size_t)dv * 4 + 1], xv.y);
            unsafeAtomicAdd(&agg[(size_t)dv * 4 + 2], xv.z);
            unsafeAtomicAdd(&agg[(size_t)dv * 4 + 3], xv.w);
        }
    }
}

__global__ void node_mlp_pool_kernel(const float4* __restrict__ x,
                                     const float4* __restrict__ agg,
                                     const int* __restrict__ batch,
                                     const float* __restrict__ eps_p,
                                     const float* __restrict__ W1,
                                     const float* __restrict__ b1,
                                     const float* __restrict__ W2,
                                     const float* __restrict__ b2,
                                     float* __restrict__ gsum,
                                     float* __restrict__ gcnt,
                                     int N) {
    int i = blockIdx.x * blockDim.x + threadIdx.x;
    bool valid = i < N;
    float o0 = 0.f, o1 = 0.f, o2 = 0.f, o3 = 0.f;
    int g = -1;
    if (valid) {
        float eps = eps_p[0];
        float4 xv = x[i];
        float4 av = agg[i];
        float h0 = (1.0f + eps) * xv.x + av.x;
        float h1 = (1.0f + eps) * xv.y + av.y;
        float h2 = (1.0f + eps) * xv.z + av.z;
        float h3 = (1.0f + eps) * xv.w + av.w;
        float tmp[16];
#pragma unroll
        for (int j = 0; j < 16; ++j) {
            float v = b1[j] + h0 * W1[j] + h1 * W1[16 + j] + h2 * W1[32 + j] + h3 * W1[48 + j];
            tmp[j] = v > 0.0f ? v : 0.0f;
        }
        float o[4];
#pragma unroll
        for (int j = 0; j < 4; ++j) {
            float v = b2[j];
#pragma unroll
            for (int k = 0; k < 16; ++k) v += tmp[k] * W2[k * 4 + j];
            o[j] = v > 0.0f ? v : 0.0f;
        }
        o0 = o[0]; o1 = o[1]; o2 = o[2]; o3 = o[3];
        g = batch[i];
    }
    int g0 = __shfl(g, 0);
    bool uni = __all(g == g0);
    if (uni && g0 >= 0) {
#pragma unroll
        for (int off = 32; off > 0; off >>= 1) {
            o0 += __shfl_down(o0, off);
            o1 += __shfl_down(o1, off);
            o2 += __shfl_down(o2, off);
            o3 += __shfl_down(o3, off);
        }
        if ((threadIdx.x & 63) == 0) {
            unsafeAtomicAdd(&gsum[(size_t)g0 * 4 + 0], o0);
            unsafeAtomicAdd(&gsum[(size_t)g0 * 4 + 1], o1);
            unsafeAtomicAdd(&gsum[(size_t)g0 * 4 + 2], o2);
            unsafeAtomicAdd(&gsum[(size_t)g0 * 4 + 3], o3);
            unsafeAtomicAdd(&gcnt[g0], 64.0f);
        }
    } else if (valid) {
        unsafeAtomicAdd(&gsum[(size_t)g * 4 + 0], o0);
        unsafeAtomicAdd(&gsum[(size_t)g * 4 + 1], o1);
        unsafeAtomicAdd(&gsum[(size_t)g * 4 + 2], o2);
        unsafeAtomicAdd(&gsum[(size_t)g * 4 + 3], o3);
        unsafeAtomicAdd(&gcnt[g], 1.0f);
    }
}

extern "C" void kernel_launch(void* const* d_in, const int* in_sizes, int n_in,
                              void* d_out, int out_size, void* d_ws, size_t ws_size,
                              hipStream_t stream) {
    const float* x     = (const float*)d_in[0];
    const int*   ei    = (const int*)d_in[1];
    const int*   batch = (const int*)d_in[2];
    const float* eps   = (const float*)d_in[3];
    const float* W1    = (const float*)d_in[4];
    const float* b1    = (const float*)d_in[5];
    const float* W2    = (const float*)d_in[6];
    const float* b2    = (const float*)d_in[7];

    const int N = in_sizes[0] / 4;
    const int E = in_sizes[1] / 2;
    const int* src = ei;
    const int* dst = ei + (size_t)E;

    const int nb = (N + BIN_SIZE - 1) >> BIN_BITS;   // 489 for N=500K
    const int epb = (E + nb - 1) / nb;
    int cap = epb + epb / 8 + 1024;                  // ~28 sigma headroom
    cap = (cap + 3) & ~3;                            // 16B-align chunk bases

    // Fast-path ws layout: packed [nb*cap] | cursor [512*CURS] |
    //                      gsum [G*4] | gcnt [G]      (4 B units)
    size_t packed_elems = ((size_t)nb * cap + 3) & ~(size_t)3;
    size_t need = (packed_elems + 512 * CURS + NUM_GRAPHS * 5) * sizeof(float);

    if (nb <= 512 && N < (1 << 19) && need <= ws_size) {
        int*   packed = (int*)d_ws;
        int*   cursor = packed + packed_elems;
        float* gsum   = (float*)(cursor + 512 * CURS);
        float* gcnt   = gsum + (size_t)NUM_GRAPHS * 4;

        // cursor + gsum + gcnt are contiguous: one async memset, no prep.
        (void)hipMemsetAsync(cursor, 0,
                             (512 * CURS + NUM_GRAPHS * 5) * sizeof(int), stream);

        int nblocks_e = (E + EB - 1) / EB;
        bin_scatter<<<nblocks_e, STH, 0, stream>>>(src, dst, packed, cursor, E, cap, nb);

        bin_accum_mlp_pool<<<nb, ACCTH, 0, stream>>>(
            (const float4*)x, packed, cursor, batch, eps,
            W1, b1, W2, b2, gsum, gcnt, N, cap);

        pool_softmax_kernel<<<(NUM_GRAPHS + 255) / 256, 256, 0, stream>>>(
            gsum, gcnt, (float*)d_out);
    } else {
        float* agg  = (float*)d_ws;
        float* gsum = agg + (size_t)N * 4;
        float* gcnt = gsum + (size_t)NUM_GRAPHS * 4;
        size_t zero_bytes = ((size_t)N * 4 + NUM_GRAPHS * 5) * sizeof(float);
        (void)hipMemsetAsync(d_ws, 0, zero_bytes, stream);

        int e4 = (E + 3) / 4;
        edge_scatter_kernel<<<(e4 + 255) / 256, 256, 0, stream>>>(
            (const float4*)x, src, dst, agg, E);

        node_mlp_pool_kernel<<<(N + 255) / 256, 256, 0, stream>>>(
            (const float4*)x, (const float4*)agg, batch, eps, W1, b1, W2, b2,
            gsum, gcnt, N);

        pool_softmax_kernel<<<(NUM_GRAPHS + 255) / 256, 256, 0, stream>>>(
            gsum, gcnt, (float*)d_out);
    }
}

// Round 7
// 432.812 us; speedup vs baseline: 1.1451x; 1.1451x over previous
//
#include <hip/hip_runtime.h>

#define NUM_GRAPHS 1024
#define BIN_BITS 10
#define BIN_SIZE (1 << BIN_BITS)      // 1024 nodes per bin
#define EB 4096                       // edges per binning block
#define STH 512                       // scatter threads (8 waves)
#define EPT 8                         // edges per thread in scatter (EB/STH)
#define SWAVES 8                      // scatter waves per block
#define CURS 16                       // cursor stride in ints (64 B = 1 line)
#define ACCTH 256                     // accum threads (4 waves)
#define ACCW 4                        // waves per accum block

typedef int v4i __attribute__((ext_vector_type(4)));  // native vec for nt-load

// ---------------------------------------------------------------------------
// Prep: x -> packed bf16x4 (8 B/node, 4 MB total: FITS the 4 MB per-XCD L2,
// unlike f32 x at 8 MB — r6 lesson: the gather table must be L2-resident,
// f32 gathers cost 523 MB of HBM fetch). Cursors/gsum/gcnt zeroed by memset.
// ---------------------------------------------------------------------------
__device__ inline unsigned bf16_rn(float f) {
    unsigned u = __float_as_uint(f);
    return (u + 0x7FFFu + ((u >> 16) & 1u)) >> 16;
}
__global__ void prep_kernel(const float4* __restrict__ x, uint2* __restrict__ x16,
                            int N) {
    int i = blockIdx.x * blockDim.x + threadIdx.x;
    if (i < N) {
        float4 v = x[i];
        uint2 r;
        r.x = bf16_rn(v.x) | (bf16_rn(v.y) << 16);
        r.y = bf16_rn(v.z) | (bf16_rn(v.w) << 16);
        x16[i] = r;
    }
}

// ---------------------------------------------------------------------------
// bin_scatter v8 (UNCHANGED control): zero per-edge atomics via ballot-match
// ranking + per-wave hist; plain stores through L2 (r4 lesson: NEVER
// nt-store scattered sub-line data). Cursors are relative counts (memset 0);
// reserve adds t*cap. packed = (dst_local << 19) | src.
// ---------------------------------------------------------------------------
__global__ void __launch_bounds__(STH, 6) bin_scatter(const int* __restrict__ src,
                                                      const int* __restrict__ dst,
                                                      int* __restrict__ packed,
                                                      int* __restrict__ cursor,
                                                      int E, int cap, int nb) {
    __shared__ int hist[SWAVES][512];     // per-wave counts (plain RMW)
    __shared__ int wbase[SWAVES][512];    // per-wave global write base per bin

    const int t = threadIdx.x;
    const int lane = t & 63;
    const int wave = t >> 6;
    const int b0 = blockIdx.x * EB;
    const int myBase = b0 + t * EPT;

    for (int j = t; j < SWAVES * 512; j += STH) (&hist[0][0])[j] = 0;
    __syncthreads();

    // ---- load 8 edges per thread (two int4 each of src/dst) ----
    int dbuf[EPT], sbuf[EPT];
    const bool full = (myBase + EPT <= E);
    if (full) {
        *(int4*)(dbuf)     = *(const int4*)(dst + myBase);
        *(int4*)(dbuf + 4) = *(const int4*)(dst + myBase + 4);
        *(int4*)(sbuf)     = *(const int4*)(src + myBase);
        *(int4*)(sbuf + 4) = *(const int4*)(src + myBase + 4);
    } else {
#pragma unroll
        for (int i = 0; i < EPT; ++i) {
            int e = myBase + i;
            bool ok = e < E;
            dbuf[i] = ok ? dst[e] : 0;
            sbuf[i] = ok ? src[e] : 0;
        }
    }

    // ---- pass A: ballot-match ranking, plain LDS RMW (no atomics) ----
    int pv[EPT];                   // packed edge values
    int bnlp[EPT];                 // (bn << 16) | lp, or -1 if invalid
#pragma unroll
    for (int k = 0; k < EPT; ++k) {
        int e = myBase + k;
        bool ok = full || (e < E);
        int d = dbuf[k];
        int bn = ((unsigned)d) >> BIN_BITS;            // < 512
        pv[k] = ((d & (BIN_SIZE - 1)) << 19) | sbuf[k];
        unsigned long long m = __ballot(ok);
#pragma unroll
        for (int bb = 0; bb < 9; ++bb) {
            unsigned long long bm = __ballot((bn >> bb) & 1);
            m &= ((bn >> bb) & 1) ? bm : ~bm;
        }
        int rank = (int)__popcll(m & ((1ull << lane) - 1ull));
        int cnt  = (int)__popcll(m);
        int leader = __ffsll((unsigned long long)m) - 1;
        int old = hist[wave][bn];                      // group lanes: same addr
        if (ok && lane == leader) hist[wave][bn] = old + cnt;
        bnlp[k] = ok ? ((bn << 16) | (old + rank)) : -1;
    }
    __syncthreads();

    // ---- combine: per-bin cross-wave prefix + single cursor reserve ----
    {
        int c[SWAVES];
        int total = 0;
#pragma unroll
        for (int w = 0; w < SWAVES; ++w) { c[w] = hist[w][t]; total += c[w]; }
        int base = t * cap;                 // cursors are relative counts
        if (t < nb && total > 0) base += atomicAdd(&cursor[t * CURS], total);
        int acc = base;
#pragma unroll
        for (int w = 0; w < SWAVES; ++w) { wbase[w][t] = acc; acc += c[w]; }
    }
    __syncthreads();

    // ---- pass B: direct scattered stores THROUGH L2 (plain, not nt) ----
    if (full) {
#pragma unroll
        for (int k = 0; k < EPT; ++k) {
            int bn = ((unsigned)bnlp[k]) >> 16;
            int lp = bnlp[k] & 0xFFFF;
            int pos = wbase[wave][bn] + lp;
            if (pos < (bn + 1) * cap)          // overflow guard (~28 sigma)
                packed[pos] = pv[k];
        }
    } else {
#pragma unroll
        for (int k = 0; k < EPT; ++k) {
            if (bnlp[k] >= 0) {
                int bn = ((unsigned)bnlp[k]) >> 16;
                int lp = bnlp[k] & 0xFFFF;
                int pos = wbase[wave][bn] + lp;
                if (pos < (bn + 1) * cap)
                    packed[pos] = pv[k];
            }
        }
    }
}

// ---------------------------------------------------------------------------
// Accum v9 = v8's software pipeline + v7's L2-resident bf16 gather table.
// Pipelined one round ahead: packed[r+1] nt-load + x16 gathers[r+1] issue
// before round r's ballot/RMW (hides the serial load->gather->RMW chain).
// Zero atomics: per-wave planes + 10-ballot match + rank-ordered RMW.
// Invalid lanes multiply by 0 (no validity ballot). Explicit A/B register
// sets (rule #20: no runtime-indexed arrays).
// ---------------------------------------------------------------------------
#define LOADR(B, PE, VM) do {                                              \
    int _i = (B) + lane * 4;                                               \
    if (_i + 3 < s1) {                                                     \
        v4i _p4 = __builtin_nontemporal_load((const v4i*)(packed + _i));   \
        PE[0] = _p4.x; PE[1] = _p4.y; PE[2] = _p4.z; PE[3] = _p4.w;        \
        VM = 0xF;                                                          \
    } else {                                                               \
        VM = 0;                                                            \
        PE[0] = (_i + 0 < s1) ? (VM |= 1, packed[_i + 0]) : 0;             \
        PE[1] = (_i + 1 < s1) ? (VM |= 2, packed[_i + 1]) : 0;             \
        PE[2] = (_i + 2 < s1) ? (VM |= 4, packed[_i + 2]) : 0;             \
        PE[3] = (_i + 3 < s1) ? (VM |= 8, packed[_i + 3]) : 0;             \
    }                                                                      \
} while (0)

#define GATHR(PE, G) do {                                                  \
    G[0] = x16[PE[0] & 0x7FFFF];                                           \
    G[1] = x16[PE[1] & 0x7FFFF];                                           \
    G[2] = x16[PE[2] & 0x7FFFF];                                           \
    G[3] = x16[PE[3] & 0x7FFFF];                                           \
} while (0)

#define PROCR(PE, G, VM) do {                                              \
    _Pragma("unroll")                                                      \
    for (int k = 0; k < 4; ++k) {                                          \
        int p = PE[k];                                                     \
        int dl = (((unsigned)p) >> 19) & (BIN_SIZE - 1);                   \
        unsigned long long m = ~0ull;                                      \
        _Pragma("unroll")                                                  \
        for (int bb = 0; bb < BIN_BITS; ++bb) {                            \
            unsigned long long bm = __ballot((dl >> bb) & 1);              \
            m &= ((dl >> bb) & 1) ? bm : ~bm;                              \
        }                                                                  \
        int rank = (int)__popcll(m & ((1ull << lane) - 1ull));             \
        float sc = ((VM >> k) & 1) ? 1.0f : 0.0f;                          \
        float v0 = __uint_as_float(G[k].x << 16) * sc;                     \
        float v1 = __uint_as_float(G[k].x & 0xFFFF0000u) * sc;             \
        float v2 = __uint_as_float(G[k].y << 16) * sc;                     \
        float v3 = __uint_as_float(G[k].y & 0xFFFF0000u) * sc;             \
        float4* pp = (float4*)&planes[wave][dl][0];                        \
        for (int pass = 0; __any(rank >= pass); ++pass) {                  \
            if (rank == pass) {                                            \
                float4 a = *pp;                                            \
                a.x += v0; a.y += v1; a.z += v2; a.w += v3;                \
                *pp = a;                                                   \
            }                                                              \
        }                                                                  \
    }                                                                      \
} while (0)

__global__ void __launch_bounds__(ACCTH) bin_accum_mlp_pool(
        const float4* __restrict__ x,
        const uint2* __restrict__ x16,
        const int* __restrict__ packed,
        const int* __restrict__ cursor,
        const int* __restrict__ batch,
        const float* __restrict__ eps_p,
        const float* __restrict__ W1, const float* __restrict__ b1,
        const float* __restrict__ W2, const float* __restrict__ b2,
        float* __restrict__ gsum, float* __restrict__ gcnt,
        int N, int cap) {
    __shared__ float planes[ACCW][BIN_SIZE][4];   // 64 KB, per-wave private

    const int bin = blockIdx.x;
    const int t = threadIdx.x;
    const int lane = t & 63;
    const int wave = t >> 6;

    // zero planes: 4096 float4s / 256 threads = 16 each
    {
        float4* pz = (float4*)&planes[0][0][0];
        float4 z; z.x = 0.f; z.y = 0.f; z.z = 0.f; z.w = 0.f;
#pragma unroll
        for (int i = 0; i < 16; ++i) pz[t + i * ACCTH] = z;
    }
    __syncthreads();

    const int start = bin * cap;
    int cnt = cursor[bin * CURS];                 // relative count
    if (cnt > cap) cnt = cap;
    if (cnt < 0) cnt = 0;
    const int end = start + cnt;

    // contiguous per-wave segments, 16B-aligned bases
    int seg = ((cnt + ACCW - 1) / ACCW + 3) & ~3;
    int s0 = start + wave * seg;
    int s1 = s0 + seg; if (s1 > end) s1 = end;

    // ---- pipelined edge loop: load/gather round r+1 before processing r ---
    if (s0 < s1) {
        int peA[4], peB[4], vmA, vmB;
        uint2 gA[4], gB[4];
        int b = s0;
        LOADR(b, peA, vmA);
        GATHR(peA, gA);
        for (;;) {
            int b1n = b + 256;
            if (b1n < s1) { LOADR(b1n, peB, vmB); GATHR(peB, gB); }
            PROCR(peA, gA, vmA);
            if (b1n >= s1) break;
            int b2n = b1n + 256;
            if (b2n < s1) { LOADR(b2n, peA, vmA); GATHR(peA, gA); }
            PROCR(peB, gB, vmB);
            if (b2n >= s1) break;
            b = b2n;
        }
    }
    __syncthreads();

    // ---- reduce 4 planes + MLP + pool; 4 node-batches of 256 ----
    const float eps = eps_p[0];
    for (int half = 0; half < 4; ++half) {
        int node = t + half * ACCTH;           // 0..1023
        float4 a = *(const float4*)&planes[0][node][0];
#pragma unroll
        for (int w = 1; w < ACCW; ++w) {
            float4 bq = *(const float4*)&planes[w][node][0];
            a.x += bq.x; a.y += bq.y; a.z += bq.z; a.w += bq.w;
        }

        int n = bin * BIN_SIZE + node;         // one node per thread
        bool valid = n < N;
        float o0 = 0.f, o1 = 0.f, o2 = 0.f, o3 = 0.f;
        int g = -1;
        if (valid) {
            float4 xv = x[n];
            float h0 = (1.0f + eps) * xv.x + a.x;
            float h1 = (1.0f + eps) * xv.y + a.y;
            float h2 = (1.0f + eps) * xv.z + a.z;
            float h3 = (1.0f + eps) * xv.w + a.w;

            float tmp[16];
#pragma unroll
            for (int j = 0; j < 16; ++j) {
                float v = b1[j] + h0 * W1[j] + h1 * W1[16 + j] + h2 * W1[32 + j] + h3 * W1[48 + j];
                tmp[j] = v > 0.0f ? v : 0.0f;
            }
            float o[4];
#pragma unroll
            for (int j = 0; j < 4; ++j) {
                float v = b2[j];
#pragma unroll
                for (int k = 0; k < 16; ++k) v += tmp[k] * W2[k * 4 + j];
                o[j] = v > 0.0f ? v : 0.0f;
            }
            o0 = o[0]; o1 = o[1]; o2 = o[2]; o3 = o[3];
            g = batch[n];
        }

        // batch is sorted -> waves almost always graph-uniform
        int g0 = __shfl(g, 0);
        bool uni = __all(g == g0);
        if (uni && g0 >= 0) {
#pragma unroll
            for (int off = 32; off > 0; off >>= 1) {
                o0 += __shfl_down(o0, off);
                o1 += __shfl_down(o1, off);
                o2 += __shfl_down(o2, off);
                o3 += __shfl_down(o3, off);
            }
            if (lane == 0) {
                unsafeAtomicAdd(&gsum[(size_t)g0 * 4 + 0], o0);
                unsafeAtomicAdd(&gsum[(size_t)g0 * 4 + 1], o1);
                unsafeAtomicAdd(&gsum[(size_t)g0 * 4 + 2], o2);
                unsafeAtomicAdd(&gsum[(size_t)g0 * 4 + 3], o3);
                unsafeAtomicAdd(&gcnt[g0], 64.0f);
            }
        } else if (valid) {
            unsafeAtomicAdd(&gsum[(size_t)g * 4 + 0], o0);
            unsafeAtomicAdd(&gsum[(size_t)g * 4 + 1], o1);
            unsafeAtomicAdd(&gsum[(size_t)g * 4 + 2], o2);
            unsafeAtomicAdd(&gsum[(size_t)g * 4 + 3], o3);
            unsafeAtomicAdd(&gcnt[g], 1.0f);
        }
    }
}

// ---------------------------------------------------------------------------
// pooled = sums / max(cnt,1); out = log_softmax per graph.
// ---------------------------------------------------------------------------
__global__ void pool_softmax_kernel(const float* __restrict__ gsum,
                                    const float* __restrict__ gcnt,
                                    float* __restrict__ out) {
    int g = blockIdx.x * blockDim.x + threadIdx.x;
    if (g >= NUM_GRAPHS) return;
    float c = fmaxf(gcnt[g], 1.0f);
    float p0 = gsum[g * 4 + 0] / c;
    float p1 = gsum[g * 4 + 1] / c;
    float p2 = gsum[g * 4 + 2] / c;
    float p3 = gsum[g * 4 + 3] / c;
    float m = fmaxf(fmaxf(p0, p1), fmaxf(p2, p3));
    float s = expf(p0 - m) + expf(p1 - m) + expf(p2 - m) + expf(p3 - m);
    float lse = m + logf(s);
    out[g * 4 + 0] = p0 - lse;
    out[g * 4 + 1] = p1 - lse;
    out[g * 4 + 2] = p2 - lse;
    out[g * 4 + 3] = p3 - lse;
}

// ---------------------------------------------------------------------------
// Fallback kernels (ws too small): direct atomic scatter + separate MLP/pool.
// ---------------------------------------------------------------------------
__global__ void edge_scatter_kernel(const float4* __restrict__ x,
                                    const int* __restrict__ src,
                                    const int* __restrict__ dst,
                                    float* __restrict__ agg,
                                    int E) {
    int t = blockIdx.x * blockDim.x + threadIdx.x;
    int e = t * 4;
    if (e + 3 < E) {
        int4 s = *(const int4*)(src + e);
        int4 d = *(const int4*)(dst + e);
        float4 xv;
        xv = x[s.x];
        unsafeAtomicAdd(&agg[(size_t)d.x * 4 + 0], xv.x);
        unsafeAtomicAdd(&agg[(size_t)d.x * 4 + 1], xv.y);
        unsafeAtomicAdd(&agg[(size_t)d.x * 4 + 2], xv.z);
        unsafeAtomicAdd(&agg[(size_t)d.x * 4 + 3], xv.w);
        xv = x[s.y];
        unsafeAtomicAdd(&agg[(size_t)d.y * 4 + 0], xv.x);
        unsafeAtomicAdd(&agg[(size_t)d.y * 4 + 1], xv.y);
        unsafeAtomicAdd(&agg[(size_t)d.y * 4 + 2], xv.z);
        unsafeAtomicAdd(&agg[(size_t)d.y * 4 + 3], xv.w);
        xv = x[s.z];
        unsafeAtomicAdd(&agg[(size_t)d.z * 4 + 0], xv.x);
        unsafeAtomicAdd(&agg[(size_t)d.z * 4 + 1], xv.y);
        unsafeAtomicAdd(&agg[(size_t)d.z * 4 + 2], xv.z);
        unsafeAtomicAdd(&agg[(size_t)d.z * 4 + 3], xv.w);
        xv = x[s.w];
        unsafeAtomicAdd(&agg[(size_t)d.w * 4 + 0], xv.x);
        unsafeAtomicAdd(&agg[(size_t)d.w * 4 + 1], xv.y);
        unsafeAtomicAdd(&agg[(size_t)d.w * 4 + 2], xv.z);
        unsafeAtomicAdd(&agg[(size_t)d.w * 4 + 3], xv.w);
    } else {
        for (int i = e; i < E; ++i) {
            int sv = src[i], dv = dst[i];
            float4 xv = x[sv];
            unsafeAtomicAdd(&agg[(size_t)dv * 4 + 0], xv.x);
            unsafeAtomicAdd(&agg[(size_t)dv * 4 + 1], xv.y);
            unsafeAtomicAdd(&agg[(size_t)dv * 4 + 2], xv.z);
            unsafeAtomicAdd(&agg[(size_t)dv * 4 + 3], xv.w);
        }
    }
}

__global__ void node_mlp_pool_kernel(const float4* __restrict__ x,
                                     const float4* __restrict__ agg,
                                     const int* __restrict__ batch,
                                     const float* __restrict__ eps_p,
                                     const float* __restrict__ W1,
                                     const float* __restrict__ b1,
                                     const float* __restrict__ W2,
                                     const float* __restrict__ b2,
                                     float* __restrict__ gsum,
                                     float* __restrict__ gcnt,
                                     int N) {
    int i = blockIdx.x * blockDim.x + threadIdx.x;
    bool valid = i < N;
    float o0 = 0.f, o1 = 0.f, o2 = 0.f, o3 = 0.f;
    int g = -1;
    if (valid) {
        float eps = eps_p[0];
        float4 xv = x[i];
        float4 av = agg[i];
        float h0 = (1.0f + eps) * xv.x + av.x;
        float h1 = (1.0f + eps) * xv.y + av.y;
        float h2 = (1.0f + eps) * xv.z + av.z;
        float h3 = (1.0f + eps) * xv.w + av.w;
        float tmp[16];
#pragma unroll
        for (int j = 0; j < 16; ++j) {
            float v = b1[j] + h0 * W1[j] + h1 * W1[16 + j] + h2 * W1[32 + j] + h3 * W1[48 + j];
            tmp[j] = v > 0.0f ? v : 0.0f;
        }
        float o[4];
#pragma unroll
        for (int j = 0; j < 4; ++j) {
            float v = b2[j];
#pragma unroll
            for (int k = 0; k < 16; ++k) v += tmp[k] * W2[k * 4 + j];
            o[j] = v > 0.0f ? v : 0.0f;
        }
        o0 = o[0]; o1 = o[1]; o2 = o[2]; o3 = o[3];
        g = batch[i];
    }
    int g0 = __shfl(g, 0);
    bool uni = __all(g == g0);
    if (uni && g0 >= 0) {
#pragma unroll
        for (int off = 32; off > 0; off >>= 1) {
            o0 += __shfl_down(o0, off);
            o1 += __shfl_down(o1, off);
            o2 += __shfl_down(o2, off);
            o3 += __shfl_down(o3, off);
        }
        if ((threadIdx.x & 63) == 0) {
            unsafeAtomicAdd(&gsum[(size_t)g0 * 4 + 0], o0);
            unsafeAtomicAdd(&gsum[(size_t)g0 * 4 + 1], o1);
            unsafeAtomicAdd(&gsum[(size_t)g0 * 4 + 2], o2);
            unsafeAtomicAdd(&gsum[(size_t)g0 * 4 + 3], o3);
            unsafeAtomicAdd(&gcnt[g0], 64.0f);
        }
    } else if (valid) {
        unsafeAtomicAdd(&gsum[(size_t)g * 4 + 0], o0);
        unsafeAtomicAdd(&gsum[(size_t)g * 4 + 1], o1);
        unsafeAtomicAdd(&gsum[(size_t)g * 4 + 2], o2);
        unsafeAtomicAdd(&gsum[(size_t)g * 4 + 3], o3);
        unsafeAtomicAdd(&gcnt[g], 1.0f);
    }
}

extern "C" void kernel_launch(void* const* d_in, const int* in_sizes, int n_in,
                              void* d_out, int out_size, void* d_ws, size_t ws_size,
                              hipStream_t stream) {
    const float* x     = (const float*)d_in[0];
    const int*   ei    = (const int*)d_in[1];
    const int*   batch = (const int*)d_in[2];
    const float* eps   = (const float*)d_in[3];
    const float* W1    = (const float*)d_in[4];
    const float* b1    = (const float*)d_in[5];
    const float* W2    = (const float*)d_in[6];
    const float* b2    = (const float*)d_in[7];

    const int N = in_sizes[0] / 4;
    const int E = in_sizes[1] / 2;
    const int* src = ei;
    const int* dst = ei + (size_t)E;

    const int nb = (N + BIN_SIZE - 1) >> BIN_BITS;   // 489 for N=500K
    const int epb = (E + nb - 1) / nb;
    int cap = epb + epb / 8 + 1024;                  // ~28 sigma headroom
    cap = (cap + 3) & ~3;                            // 16B-align chunk bases

    // Fast-path ws layout: x16 [2N] | packed [nb*cap] | cursor [512*CURS] |
    //                      gsum [G*4] | gcnt [G]      (4 B units)
    size_t x16_elems = ((size_t)2 * N + 3) & ~(size_t)3;
    size_t packed_elems = ((size_t)nb * cap + 3) & ~(size_t)3;
    size_t need = (x16_elems + packed_elems + 512 * CURS + NUM_GRAPHS * 5) * sizeof(float);

    if (nb <= 512 && N < (1 << 19) && need <= ws_size) {
        uint2* x16    = (uint2*)d_ws;
        int*   packed = (int*)d_ws + x16_elems;
        int*   cursor = packed + packed_elems;
        float* gsum   = (float*)(cursor + 512 * CURS);
        float* gcnt   = gsum + (size_t)NUM_GRAPHS * 4;

        // cursor + gsum + gcnt are contiguous: one async memset.
        (void)hipMemsetAsync(cursor, 0,
                             (512 * CURS + NUM_GRAPHS * 5) * sizeof(int), stream);

        prep_kernel<<<(N + 511) / 512, 512, 0, stream>>>((const float4*)x, x16, N);

        int nblocks_e = (E + EB - 1) / EB;
        bin_scatter<<<nblocks_e, STH, 0, stream>>>(src, dst, packed, cursor, E, cap, nb);

        bin_accum_mlp_pool<<<nb, ACCTH, 0, stream>>>(
            (const float4*)x, (const uint2*)x16, packed, cursor, batch, eps,
            W1, b1, W2, b2, gsum, gcnt, N, cap);

        pool_softmax_kernel<<<(NUM_GRAPHS + 255) / 256, 256, 0, stream>>>(
            gsum, gcnt, (float*)d_out);
    } else {
        float* agg  = (float*)d_ws;
        float* gsum = agg + (size_t)N * 4;
        float* gcnt = gsum + (size_t)NUM_GRAPHS * 4;
        size_t zero_bytes = ((size_t)N * 4 + NUM_GRAPHS * 5) * sizeof(float);
        (void)hipMemsetAsync(d_ws, 0, zero_bytes, stream);

        int e4 = (E + 3) / 4;
        edge_scatter_kernel<<<(e4 + 255) / 256, 256, 0, stream>>>(
            (const float4*)x, src, dst, agg, E);

        node_mlp_pool_kernel<<<(N + 255) / 256, 256, 0, stream>>>(
            (const float4*)x, (const float4*)agg, batch, eps, W1, b1, W2, b2,
            gsum, gcnt, N);

        pool_softmax_kernel<<<(NUM_GRAPHS + 255) / 256, 256, 0, stream>>>(
            gsum, gcnt, (float*)d_out);
    }
}

// Round 8
// 429.646 us; speedup vs baseline: 1.1535x; 1.0074x over previous
//
#include <hip/hip_runtime.h>

#define NUM_GRAPHS 1024
#define BIN_BITS 10
#define BIN_SIZE (1 << BIN_BITS)      // 1024 nodes per bin
#define EB 4096                       // edges per binning block
#define STH 512                       // scatter threads (8 waves)
#define EPT 8                         // edges per thread in scatter (EB/STH)
#define SWAVES 8                      // scatter waves per block
#define CURS 16                       // cursor stride in ints (64 B = 1 line)
#define ACCTH 256                     // accum threads (4 waves)
#define ACCW 4                        // waves per accum block

typedef int v4i __attribute__((ext_vector_type(4)));  // native vec for nt-load

__device__ inline unsigned bf16_rn(float f) {
    unsigned u = __float_as_uint(f);
    return (u + 0x7FFFu + ((u >> 16) & 1u)) >> 16;
}

// ---------------------------------------------------------------------------
// bin_scatter v9 = v8 + prep folded in as phase 0 (x -> bf16x4 table; 4 MB,
// L2-resident — r6 lesson: f32 gathers at 8 MB miss L2 and cost 523 MB HBM).
// Scatter itself unchanged: zero per-edge atomics via ballot-match ranking +
// per-wave hist; plain stores through L2 (r4 lesson: NEVER nt-store
// scattered sub-line data). Cursors relative (memset 0), reserve adds t*cap.
// packed = (dst_local << 19) | src.
// ---------------------------------------------------------------------------
__global__ void __launch_bounds__(STH, 6) bin_scatter(const float4* __restrict__ x,
                                                      uint2* __restrict__ x16,
                                                      const int* __restrict__ src,
                                                      const int* __restrict__ dst,
                                                      int* __restrict__ packed,
                                                      int* __restrict__ cursor,
                                                      int N, int E, int cap, int nb) {
    __shared__ int hist[SWAVES][512];     // per-wave counts (plain RMW)
    __shared__ int wbase[SWAVES][512];    // per-wave global write base per bin

    const int t = threadIdx.x;
    const int lane = t & 63;
    const int wave = t >> 6;
    const int b0 = blockIdx.x * EB;
    const int myBase = b0 + t * EPT;

    // ---- phase 0: prep (was its own kernel; scatter never reads x16,
    //      the scatter->accum kernel boundary is the required sync) ----
    {
        int nd = blockIdx.x * STH + t;
        if (nd < N) {
            float4 v = x[nd];
            uint2 r;
            r.x = bf16_rn(v.x) | (bf16_rn(v.y) << 16);
            r.y = bf16_rn(v.z) | (bf16_rn(v.w) << 16);
            x16[nd] = r;
        }
    }

    for (int j = t; j < SWAVES * 512; j += STH) (&hist[0][0])[j] = 0;
    __syncthreads();

    // ---- load 8 edges per thread (two int4 each of src/dst) ----
    int dbuf[EPT], sbuf[EPT];
    const bool full = (myBase + EPT <= E);
    if (full) {
        *(int4*)(dbuf)     = *(const int4*)(dst + myBase);
        *(int4*)(dbuf + 4) = *(const int4*)(dst + myBase + 4);
        *(int4*)(sbuf)     = *(const int4*)(src + myBase);
        *(int4*)(sbuf + 4) = *(const int4*)(src + myBase + 4);
    } else {
#pragma unroll
        for (int i = 0; i < EPT; ++i) {
            int e = myBase + i;
            bool ok = e < E;
            dbuf[i] = ok ? dst[e] : 0;
            sbuf[i] = ok ? src[e] : 0;
        }
    }

    // ---- pass A: ballot-match ranking, plain LDS RMW (no atomics) ----
    int pv[EPT];                   // packed edge values
    int bnlp[EPT];                 // (bn << 16) | lp, or -1 if invalid
#pragma unroll
    for (int k = 0; k < EPT; ++k) {
        int e = myBase + k;
        bool ok = full || (e < E);
        int d = dbuf[k];
        int bn = ((unsigned)d) >> BIN_BITS;            // < 512
        pv[k] = ((d & (BIN_SIZE - 1)) << 19) | sbuf[k];
        unsigned long long m = __ballot(ok);
#pragma unroll
        for (int bb = 0; bb < 9; ++bb) {
            unsigned long long bm = __ballot((bn >> bb) & 1);
            m &= ((bn >> bb) & 1) ? bm : ~bm;
        }
        int rank = (int)__popcll(m & ((1ull << lane) - 1ull));
        int cnt  = (int)__popcll(m);
        int leader = __ffsll((unsigned long long)m) - 1;
        int old = hist[wave][bn];                      // group lanes: same addr
        if (ok && lane == leader) hist[wave][bn] = old + cnt;
        bnlp[k] = ok ? ((bn << 16) | (old + rank)) : -1;
    }
    __syncthreads();

    // ---- combine: per-bin cross-wave prefix + single cursor reserve ----
    {
        int c[SWAVES];
        int total = 0;
#pragma unroll
        for (int w = 0; w < SWAVES; ++w) { c[w] = hist[w][t]; total += c[w]; }
        int base = t * cap;                 // cursors are relative counts
        if (t < nb && total > 0) base += atomicAdd(&cursor[t * CURS], total);
        int acc = base;
#pragma unroll
        for (int w = 0; w < SWAVES; ++w) { wbase[w][t] = acc; acc += c[w]; }
    }
    __syncthreads();

    // ---- pass B: direct scattered stores THROUGH L2 (plain, not nt) ----
    if (full) {
#pragma unroll
        for (int k = 0; k < EPT; ++k) {
            int bn = ((unsigned)bnlp[k]) >> 16;
            int lp = bnlp[k] & 0xFFFF;
            int pos = wbase[wave][bn] + lp;
            if (pos < (bn + 1) * cap)          // overflow guard (~28 sigma)
                packed[pos] = pv[k];
        }
    } else {
#pragma unroll
        for (int k = 0; k < EPT; ++k) {
            if (bnlp[k] >= 0) {
                int bn = ((unsigned)bnlp[k]) >> 16;
                int lp = bnlp[k] & 0xFFFF;
                int pos = wbase[wave][bn] + lp;
                if (pos < (bn + 1) * cap)
                    packed[pos] = pv[k];
            }
        }
    }
}

// ---------------------------------------------------------------------------
// Accum v10: leader-gather SINGLE-PASS RMW. r7 post-mortem: the rank-ordered
// multi-pass RMW was the stall — each pass is a dependent ds_read_b128 ->
// add -> ds_write chain (~130-140 cy) and ~2 same-dl pairs/64 lanes made it
// run 2-3 passes nearly every k-step. Now: after the 10-ballot match, the
// group LEADER gathers members' values via __shfl (bpermute reads source
// regs regardless of exec; members keep rem=0 and never modify their regs,
// so the leader reads pristine values), then ONE RMW per group, always.
// Cross-k same-dl ordering stays correct: LDS ops issue in wave program
// order. Pipelined load/gather kept from v9 (neutral, not harmful).
// ---------------------------------------------------------------------------
#define LOADR(B, PE, VM) do {                                              \
    int _i = (B) + lane * 4;                                               \
    if (_i + 3 < s1) {                                                     \
        v4i _p4 = __builtin_nontemporal_load((const v4i*)(packed + _i));   \
        PE[0] = _p4.x; PE[1] = _p4.y; PE[2] = _p4.z; PE[3] = _p4.w;        \
        VM = 0xF;                                                          \
    } else {                                                               \
        VM = 0;                                                            \
        PE[0] = (_i + 0 < s1) ? (VM |= 1, packed[_i + 0]) : 0;             \
        PE[1] = (_i + 1 < s1) ? (VM |= 2, packed[_i + 1]) : 0;             \
        PE[2] = (_i + 2 < s1) ? (VM |= 4, packed[_i + 2]) : 0;             \
        PE[3] = (_i + 3 < s1) ? (VM |= 8, packed[_i + 3]) : 0;             \
    }                                                                      \
} while (0)

#define GATHR(PE, G) do {                                                  \
    G[0] = x16[PE[0] & 0x7FFFF];                                           \
    G[1] = x16[PE[1] & 0x7FFFF];                                           \
    G[2] = x16[PE[2] & 0x7FFFF];                                           \
    G[3] = x16[PE[3] & 0x7FFFF];                                           \
} while (0)

#define PROCR(PE, G, VM) do {                                              \
    _Pragma("unroll")                                                      \
    for (int k = 0; k < 4; ++k) {                                          \
        int p = PE[k];                                                     \
        int dl = (((unsigned)p) >> 19) & (BIN_SIZE - 1);                   \
        unsigned long long m = ~0ull;                                      \
        _Pragma("unroll")                                                  \
        for (int bb = 0; bb < BIN_BITS; ++bb) {                            \
            unsigned long long bm = __ballot((dl >> bb) & 1);              \
            m &= ((dl >> bb) & 1) ? bm : ~bm;                              \
        }                                                                  \
        int rank = (int)__popcll(m & ((1ull << lane) - 1ull));             \
        float sc = ((VM >> k) & 1) ? 1.0f : 0.0f;                          \
        float v0 = __uint_as_float(G[k].x << 16) * sc;                     \
        float v1 = __uint_as_float(G[k].x & 0xFFFF0000u) * sc;             \
        float v2 = __uint_as_float(G[k].y << 16) * sc;                     \
        float v3 = __uint_as_float(G[k].y & 0xFFFF0000u) * sc;             \
        /* leader gathers members (usually 0-1 iterations) */              \
        unsigned long long rem =                                           \
            (rank == 0) ? (m & ~(1ull << lane)) : 0ull;                    \
        while (__any(rem != 0)) {                                          \
            int srcl = rem ? (__ffsll((unsigned long long)rem) - 1) : 0;   \
            float t0 = __shfl(v0, srcl);                                   \
            float t1 = __shfl(v1, srcl);                                   \
            float t2 = __shfl(v2, srcl);                                   \
            float t3 = __shfl(v3, srcl);                                   \
            if (rem) { v0 += t0; v1 += t1; v2 += t2; v3 += t3;             \
                       rem &= rem - 1; }                                   \
        }                                                                  \
        if (rank == 0) {                                                   \
            float4* pp = (float4*)&planes[wave][dl][0];                    \
            float4 a = *pp;                                                \
            a.x += v0; a.y += v1; a.z += v2; a.w += v3;                    \
            *pp = a;                                                       \
        }                                                                  \
    }                                                                      \
} while (0)

__global__ void __launch_bounds__(ACCTH) bin_accum_mlp_pool(
        const float4* __restrict__ x,
        const uint2* __restrict__ x16,
        const int* __restrict__ packed,
        const int* __restrict__ cursor,
        const int* __restrict__ batch,
        const float* __restrict__ eps_p,
        const float* __restrict__ W1, const float* __restrict__ b1,
        const float* __restrict__ W2, const float* __restrict__ b2,
        float* __restrict__ gsum, float* __restrict__ gcnt,
        int N, int cap) {
    __shared__ float planes[ACCW][BIN_SIZE][4];   // 64 KB, per-wave private

    const int bin = blockIdx.x;
    const int t = threadIdx.x;
    const int lane = t & 63;
    const int wave = t >> 6;

    // zero planes: 4096 float4s / 256 threads = 16 each
    {
        float4* pz = (float4*)&planes[0][0][0];
        float4 z; z.x = 0.f; z.y = 0.f; z.z = 0.f; z.w = 0.f;
#pragma unroll
        for (int i = 0; i < 16; ++i) pz[t + i * ACCTH] = z;
    }
    __syncthreads();

    const int start = bin * cap;
    int cnt = cursor[bin * CURS];                 // relative count
    if (cnt > cap) cnt = cap;
    if (cnt < 0) cnt = 0;
    const int end = start + cnt;

    // contiguous per-wave segments, 16B-aligned bases
    int seg = ((cnt + ACCW - 1) / ACCW + 3) & ~3;
    int s0 = start + wave * seg;
    int s1 = s0 + seg; if (s1 > end) s1 = end;

    // ---- pipelined edge loop: load/gather round r+1 before processing r ---
    if (s0 < s1) {
        int peA[4], peB[4], vmA, vmB;
        uint2 gA[4], gB[4];
        int b = s0;
        LOADR(b, peA, vmA);
        GATHR(peA, gA);
        for (;;) {
            int b1n = b + 256;
            if (b1n < s1) { LOADR(b1n, peB, vmB); GATHR(peB, gB); }
            PROCR(peA, gA, vmA);
            if (b1n >= s1) break;
            int b2n = b1n + 256;
            if (b2n < s1) { LOADR(b2n, peA, vmA); GATHR(peA, gA); }
            PROCR(peB, gB, vmB);
            if (b2n >= s1) break;
            b = b2n;
        }
    }
    __syncthreads();

    // ---- reduce 4 planes + MLP + pool; 4 node-batches of 256 ----
    const float eps = eps_p[0];
    for (int half = 0; half < 4; ++half) {
        int node = t + half * ACCTH;           // 0..1023
        float4 a = *(const float4*)&planes[0][node][0];
#pragma unroll
        for (int w = 1; w < ACCW; ++w) {
            float4 bq = *(const float4*)&planes[w][node][0];
            a.x += bq.x; a.y += bq.y; a.z += bq.z; a.w += bq.w;
        }

        int n = bin * BIN_SIZE + node;         // one node per thread
        bool valid = n < N;
        float o0 = 0.f, o1 = 0.f, o2 = 0.f, o3 = 0.f;
        int g = -1;
        if (valid) {
            float4 xv = x[n];
            float h0 = (1.0f + eps) * xv.x + a.x;
            float h1 = (1.0f + eps) * xv.y + a.y;
            float h2 = (1.0f + eps) * xv.z + a.z;
            float h3 = (1.0f + eps) * xv.w + a.w;

            float tmp[16];
#pragma unroll
            for (int j = 0; j < 16; ++j) {
                float v = b1[j] + h0 * W1[j] + h1 * W1[16 + j] + h2 * W1[32 + j] + h3 * W1[48 + j];
                tmp[j] = v > 0.0f ? v : 0.0f;
            }
            float o[4];
#pragma unroll
            for (int j = 0; j < 4; ++j) {
                float v = b2[j];
#pragma unroll
                for (int k = 0; k < 16; ++k) v += tmp[k] * W2[k * 4 + j];
                o[j] = v > 0.0f ? v : 0.0f;
            }
            o0 = o[0]; o1 = o[1]; o2 = o[2]; o3 = o[3];
            g = batch[n];
        }

        // batch is sorted -> waves almost always graph-uniform
        int g0 = __shfl(g, 0);
        bool uni = __all(g == g0);
        if (uni && g0 >= 0) {
#pragma unroll
            for (int off = 32; off > 0; off >>= 1) {
                o0 += __shfl_down(o0, off);
                o1 += __shfl_down(o1, off);
                o2 += __shfl_down(o2, off);
                o3 += __shfl_down(o3, off);
            }
            if (lane == 0) {
                unsafeAtomicAdd(&gsum[(size_t)g0 * 4 + 0], o0);
                unsafeAtomicAdd(&gsum[(size_t)g0 * 4 + 1], o1);
                unsafeAtomicAdd(&gsum[(size_t)g0 * 4 + 2], o2);
                unsafeAtomicAdd(&gsum[(size_t)g0 * 4 + 3], o3);
                unsafeAtomicAdd(&gcnt[g0], 64.0f);
            }
        } else if (valid) {
            unsafeAtomicAdd(&gsum[(size_t)g * 4 + 0], o0);
            unsafeAtomicAdd(&gsum[(size_t)g * 4 + 1], o1);
            unsafeAtomicAdd(&gsum[(size_t)g * 4 + 2], o2);
            unsafeAtomicAdd(&gsum[(size_t)g * 4 + 3], o3);
            unsafeAtomicAdd(&gcnt[g], 1.0f);
        }
    }
}

// ---------------------------------------------------------------------------
// pooled = sums / max(cnt,1); out = log_softmax per graph.
// ---------------------------------------------------------------------------
__global__ void pool_softmax_kernel(const float* __restrict__ gsum,
                                    const float* __restrict__ gcnt,
                                    float* __restrict__ out) {
    int g = blockIdx.x * blockDim.x + threadIdx.x;
    if (g >= NUM_GRAPHS) return;
    float c = fmaxf(gcnt[g], 1.0f);
    float p0 = gsum[g * 4 + 0] / c;
    float p1 = gsum[g * 4 + 1] / c;
    float p2 = gsum[g * 4 + 2] / c;
    float p3 = gsum[g * 4 + 3] / c;
    float m = fmaxf(fmaxf(p0, p1), fmaxf(p2, p3));
    float s = expf(p0 - m) + expf(p1 - m) + expf(p2 - m) + expf(p3 - m);
    float lse = m + logf(s);
    out[g * 4 + 0] = p0 - lse;
    out[g * 4 + 1] = p1 - lse;
    out[g * 4 + 2] = p2 - lse;
    out[g * 4 + 3] = p3 - lse;
}

// ---------------------------------------------------------------------------
// Fallback kernels (ws too small): direct atomic scatter + separate MLP/pool.
// ---------------------------------------------------------------------------
__global__ void edge_scatter_kernel(const float4* __restrict__ x,
                                    const int* __restrict__ src,
                                    const int* __restrict__ dst,
                                    float* __restrict__ agg,
                                    int E) {
    int t = blockIdx.x * blockDim.x + threadIdx.x;
    int e = t * 4;
    if (e + 3 < E) {
        int4 s = *(const int4*)(src + e);
        int4 d = *(const int4*)(dst + e);
        float4 xv;
        xv = x[s.x];
        unsafeAtomicAdd(&agg[(size_t)d.x * 4 + 0], xv.x);
        unsafeAtomicAdd(&agg[(size_t)d.x * 4 + 1], xv.y);
        unsafeAtomicAdd(&agg[(size_t)d.x * 4 + 2], xv.z);
        unsafeAtomicAdd(&agg[(size_t)d.x * 4 + 3], xv.w);
        xv = x[s.y];
        unsafeAtomicAdd(&agg[(size_t)d.y * 4 + 0], xv.x);
        unsafeAtomicAdd(&agg[(size_t)d.y * 4 + 1], xv.y);
        unsafeAtomicAdd(&agg[(size_t)d.y * 4 + 2], xv.z);
        unsafeAtomicAdd(&agg[(size_t)d.y * 4 + 3], xv.w);
        xv = x[s.z];
        unsafeAtomicAdd(&agg[(size_t)d.z * 4 + 0], xv.x);
        unsafeAtomicAdd(&agg[(size_t)d.z * 4 + 1], xv.y);
        unsafeAtomicAdd(&agg[(size_t)d.z * 4 + 2], xv.z);
        unsafeAtomicAdd(&agg[(size_t)d.z * 4 + 3], xv.w);
        xv = x[s.w];
        unsafeAtomicAdd(&agg[(size_t)d.w * 4 + 0], xv.x);
        unsafeAtomicAdd(&agg[(size_t)d.w * 4 + 1], xv.y);
        unsafeAtomicAdd(&agg[(size_t)d.w * 4 + 2], xv.z);
        unsafeAtomicAdd(&agg[(size_t)d.w * 4 + 3], xv.w);
    } else {
        for (int i = e; i < E; ++i) {
            int sv = src[i], dv = dst[i];
            float4 xv = x[sv];
            unsafeAtomicAdd(&agg[(size_t)dv * 4 + 0], xv.x);
            unsafeAtomicAdd(&agg[(size_t)dv * 4 + 1], xv.y);
            unsafeAtomicAdd(&agg[(size_t)dv * 4 + 2], xv.z);
            unsafeAtomicAdd(&agg[(size_t)dv * 4 + 3], xv.w);
        }
    }
}

__global__ void node_mlp_pool_kernel(const float4* __restrict__ x,
                                     const float4* __restrict__ agg,
                                     const int* __restrict__ batch,
                                     const float* __restrict__ eps_p,
                                     const float* __restrict__ W1,
                                     const float* __restrict__ b1,
                                     const float* __restrict__ W2,
                                     const float* __restrict__ b2,
                                     float* __restrict__ gsum,
                                     float* __restrict__ gcnt,
                                     int N) {
    int i = blockIdx.x * blockDim.x + threadIdx.x;
    bool valid = i < N;
    float o0 = 0.f, o1 = 0.f, o2 = 0.f, o3 = 0.f;
    int g = -1;
    if (valid) {
        float eps = eps_p[0];
        float4 xv = x[i];
        float4 av = agg[i];
        float h0 = (1.0f + eps) * xv.x + av.x;
        float h1 = (1.0f + eps) * xv.y + av.y;
        float h2 = (1.0f + eps) * xv.z + av.z;
        float h3 = (1.0f + eps) * xv.w + av.w;
        float tmp[16];
#pragma unroll
        for (int j = 0; j < 16; ++j) {
            float v = b1[j] + h0 * W1[j] + h1 * W1[16 + j] + h2 * W1[32 + j] + h3 * W1[48 + j];
            tmp[j] = v > 0.0f ? v : 0.0f;
        }
        float o[4];
#pragma unroll
        for (int j = 0; j < 4; ++j) {
            float v = b2[j];
#pragma unroll
            for (int k = 0; k < 16; ++k) v += tmp[k] * W2[k * 4 + j];
            o[j] = v > 0.0f ? v : 0.0f;
        }
        o0 = o[0]; o1 = o[1]; o2 = o[2]; o3 = o[3];
        g = batch[i];
    }
    int g0 = __shfl(g, 0);
    bool uni = __all(g == g0);
    if (uni && g0 >= 0) {
#pragma unroll
        for (int off = 32; off > 0; off >>= 1) {
            o0 += __shfl_down(o0, off);
            o1 += __shfl_down(o1, off);
            o2 += __shfl_down(o2, off);
            o3 += __shfl_down(o3, off);
        }
        if ((threadIdx.x & 63) == 0) {
            unsafeAtomicAdd(&gsum[(size_t)g0 * 4 + 0], o0);
            unsafeAtomicAdd(&gsum[(size_t)g0 * 4 + 1], o1);
            unsafeAtomicAdd(&gsum[(size_t)g0 * 4 + 2], o2);
            unsafeAtomicAdd(&gsum[(size_t)g0 * 4 + 3], o3);
            unsafeAtomicAdd(&gcnt[g0], 64.0f);
        }
    } else if (valid) {
        unsafeAtomicAdd(&gsum[(size_t)g * 4 + 0], o0);
        unsafeAtomicAdd(&gsum[(size_t)g * 4 + 1], o1);
        unsafeAtomicAdd(&gsum[(size_t)g * 4 + 2], o2);
        unsafeAtomicAdd(&gsum[(size_t)g * 4 + 3], o3);
        unsafeAtomicAdd(&gcnt[g], 1.0f);
    }
}

extern "C" void kernel_launch(void* const* d_in, const int* in_sizes, int n_in,
                              void* d_out, int out_size, void* d_ws, size_t ws_size,
                              hipStream_t stream) {
    const float* x     = (const float*)d_in[0];
    const int*   ei    = (const int*)d_in[1];
    const int*   batch = (const int*)d_in[2];
    const float* eps   = (const float*)d_in[3];
    const float* W1    = (const float*)d_in[4];
    const float* b1    = (const float*)d_in[5];
    const float* W2    = (const float*)d_in[6];
    const float* b2    = (const float*)d_in[7];

    const int N = in_sizes[0] / 4;
    const int E = in_sizes[1] / 2;
    const int* src = ei;
    const int* dst = ei + (size_t)E;

    const int nb = (N + BIN_SIZE - 1) >> BIN_BITS;   // 489 for N=500K
    const int epb = (E + nb - 1) / nb;
    int cap = epb + epb / 8 + 1024;                  // ~28 sigma headroom
    cap = (cap + 3) & ~3;                            // 16B-align chunk bases

    // Fast-path ws layout: x16 [2N] | packed [nb*cap] | cursor [512*CURS] |
    //                      gsum [G*4] | gcnt [G]      (4 B units)
    size_t x16_elems = ((size_t)2 * N + 3) & ~(size_t)3;
    size_t packed_elems = ((size_t)nb * cap + 3) & ~(size_t)3;
    size_t need = (x16_elems + packed_elems + 512 * CURS + NUM_GRAPHS * 5) * sizeof(float);

    // prep coverage check: scatter grid must span N nodes in phase 0
    int nblocks_e = (E + EB - 1) / EB;
    bool prep_ok = (size_t)nblocks_e * STH >= (size_t)N;

    if (nb <= 512 && N < (1 << 19) && need <= ws_size && prep_ok) {
        uint2* x16    = (uint2*)d_ws;
        int*   packed = (int*)d_ws + x16_elems;
        int*   cursor = packed + packed_elems;
        float* gsum   = (float*)(cursor + 512 * CURS);
        float* gcnt   = gsum + (size_t)NUM_GRAPHS * 4;

        // cursor + gsum + gcnt are contiguous: one async memset.
        (void)hipMemsetAsync(cursor, 0,
                             (512 * CURS + NUM_GRAPHS * 5) * sizeof(int), stream);

        bin_scatter<<<nblocks_e, STH, 0, stream>>>(
            (const float4*)x, x16, src, dst, packed, cursor, N, E, cap, nb);

        bin_accum_mlp_pool<<<nb, ACCTH, 0, stream>>>(
            (const float4*)x, (const uint2*)x16, packed, cursor, batch, eps,
            W1, b1, W2, b2, gsum, gcnt, N, cap);

        pool_softmax_kernel<<<(NUM_GRAPHS + 255) / 256, 256, 0, stream>>>(
            gsum, gcnt, (float*)d_out);
    } else {
        float* agg  = (float*)d_ws;
        float* gsum = agg + (size_t)N * 4;
        float* gcnt = gsum + (size_t)NUM_GRAPHS * 4;
        size_t zero_bytes = ((size_t)N * 4 + NUM_GRAPHS * 5) * sizeof(float);
        (void)hipMemsetAsync(d_ws, 0, zero_bytes, stream);

        int e4 = (E + 3) / 4;
        edge_scatter_kernel<<<(e4 + 255) / 256, 256, 0, stream>>>(
            (const float4*)x, src, dst, agg, E);

        node_mlp_pool_kernel<<<(N + 255) / 256, 256, 0, stream>>>(
            (const float4*)x, (const float4*)agg, batch, eps, W1, b1, W2, b2,
            gsum, gcnt, N);

        pool_softmax_kernel<<<(NUM_GRAPHS + 255) / 256, 256, 0, stream>>>(
            gsum, gcnt, (float*)d_out);
    }
}